// Round 1
// baseline (170.091 us; speedup 1.0000x reference)
//
#include <hip/hip_runtime.h>
#include <hip/hip_bf16.h>

// Problem constants
#define CO    128
#define CI    128
#define NPIX  3136   // 56*56
#define PH    58
#define PPIX  3364   // 58*58
#define HPX   232    // halo pixels per block: 4 padded rows * 58
#define SROW  272    // LDS bytes per halo pixel: 256 data + 16 pad (bank balance)

typedef __bf16 bf16x8 __attribute__((ext_vector_type(8)));
typedef float  f32x4  __attribute__((ext_vector_type(4)));

// ---------------------------------------------------------------------------
// Fused prep: [0,2048) weights | [2048,2504) border zero | [2504,4072) transpose.
// (unchanged from previous round)
// ---------------------------------------------------------------------------
__global__ void prep_all(const float* __restrict__ in,
                         const float* __restrict__ eps,
                         const float* __restrict__ psi,
                         const float* __restrict__ mu,
                         __bf16* __restrict__ wt,
                         __bf16* __restrict__ it) {
  __shared__ __align__(16) __bf16 T[64][136];
  const int bx = blockIdx.x, tid = threadIdx.x;

  if (bx < 2048) {
    int idx = bx * 256 + tid;               // = (b*CO+co)*CI+ci
    int ci = idx & 127;
    int co = (idx >> 7) & 127;
    const float* e  = eps + (size_t)idx * 9;
    const float* ps = psi + (size_t)(co * CI + ci) * 9;
    const float* m  = mu  + (size_t)(co * CI + ci) * 9;
    float v[9];
#pragma unroll
    for (int p = 0; p < 9; ++p) v[p] = e[p] * __expf(ps[p]) + m[p];
    int b = idx >> 14;
    __bf16* w = wt + ((size_t)b * 9 * CO + co) * CI + ci;
#pragma unroll
    for (int p = 0; p < 9; ++p) w[(size_t)p * CO * CI] = (__bf16)v[p];
  } else if (bx < 2504) {
    int cid = (bx - 2048) * 256 + tid;
    int pid = cid >> 4;
    int chunk = cid & 15;
    int b = pid / 228;
    int e = pid - b * 228;
    int ph, pw;
    if (e < 58)       { ph = 0;       pw = e; }
    else if (e < 116) { ph = 57;      pw = e - 58; }
    else if (e < 172) { ph = e - 115; pw = 0; }
    else              { ph = e - 171; pw = 57; }
    f32x4 z = {0.f, 0.f, 0.f, 0.f};
    *(f32x4*)&it[((size_t)b * PPIX + ph * PH + pw) * CI + chunk * 8] = z;
  } else {
    int tx = bx - 2504;
    int b  = tx / 49;
    int p0 = (tx - b * 49) * 64;
    const float* src = in + (size_t)b * CI * NPIX;
#pragma unroll
    for (int jj = 0; jj < 8; ++jj) {
      int c = jj * 256 + tid;
      int ci = c >> 4, xc = c & 15;
      float4 v = *(const float4*)(src + (size_t)ci * NPIX + p0 + xc * 4);
      T[xc * 4 + 0][ci] = (__bf16)v.x;
      T[xc * 4 + 1][ci] = (__bf16)v.y;
      T[xc * 4 + 2][ci] = (__bf16)v.z;
      T[xc * 4 + 3][ci] = (__bf16)v.w;
    }
    __syncthreads();
    __bf16* dstb = it + (size_t)b * PPIX * CI;
#pragma unroll
    for (int jj = 0; jj < 4; ++jj) {
      int c = jj * 256 + tid;
      int pl = c >> 4, xc = c & 15;
      int pix = p0 + pl;
      int oh = pix / 56, ow = pix - oh * 56;
      int ppix = (oh + 1) * PH + (ow + 1);
      *(f32x4*)&dstb[(size_t)ppix * CI + xc * 8] = *(const f32x4*)&T[pl][xc * 8];
    }
  }
}

// ---------------------------------------------------------------------------
// GEMM/conv, barrier-free K-loop, kg-split for B-fragment reuse:
//   block = 128 co x 112 n (2 full image rows), 4 waves = 2 co-groups(64co)
//   x 2 K-groups(64ci). Each wave: 4 m-frags x 7 n-frags -> each 1KB B LDS
//   read feeds 4 MFMAs (was 2) and total B-read volume halves.
//   Prologue: stage the 4-row halo into LDS once, ONE __syncthreads.
//   K-loop (9 taps x 2 ci-chunks = 18 steps): B from LDS, A global->VGPR
//   with 2-step register prefetch ring (covers ~200cy L2 latency). No
//   barriers in the loop. Epilogue: kg=1 waves dump acc to LDS (reusing
//   halo buffer, 2x28KB), kg=0 waves add + store.
//   Grid 28 tiles x 32 batch = 896 blocks; LDS 63104B -> 2 blocks/CU.
// ---------------------------------------------------------------------------
__global__ __launch_bounds__(256) void bconv_gemm(
    const __bf16* __restrict__ wt,   // [b][9][128 co][128 ci]
    const __bf16* __restrict__ it,   // [b][3364 pix][128 ci]
    float* __restrict__ out) {       // [b][128 co][3136 n]
  __shared__ __align__(16) char Bsh[HPX * SROW];   // 63104 B
  const int tid  = threadIdx.x;
  const int w    = tid >> 6;
  const int lane = tid & 63;
  const int quad = lane >> 4;
  const int l15  = lane & 15;
  const int cg   = w & 1;            // co-group: co [cg*64, cg*64+64)
  const int kg   = w >> 1;           // K-group: ci [kg*64, kg*64+64)

  // Decode: lin = x + 8*(tile*4 + bhi); b = x + 8*bhi  -> same-b blocks share an XCD
  const int lin = blockIdx.x;
  const int x   = lin & 7;
  const int j   = lin >> 3;          // 0..111
  const int bhi = j & 3;
  const int tile = j >> 2;           // 0..27
  const int b   = x + 8 * bhi;
  const int oh0 = tile * 2;          // first output row of this tile

  // ---- prologue: stage halo (padded rows oh0..oh0+3, contiguous) ----
  const __bf16* hsrc = it + ((size_t)b * PPIX + oh0 * PH) * CI;
#pragma unroll
  for (int i = 0; i < 15; ++i) {
    int idx = i * 256 + tid;                 // 16B chunk id, 3712 total
    if (idx < HPX * 16) {
      int px = idx >> 4, sub = idx & 15;
      f32x4 v = *(const f32x4*)(hsrc + (size_t)idx * 8);
      *(f32x4*)&Bsh[px * SROW + sub * 16] = v;
    }
  }
  __syncthreads();

  // ---- per-lane B fragment LDS byte-bases (tap (0,0), this wave's ci half) ----
  int bbase[7];
#pragma unroll
  for (int nf = 0; nf < 7; ++nf) {
    int n = nf * 16 + l15;                   // 0..111
    int r = (n >= 56) ? 1 : 0;
    int c = n - r * 56;
    bbase[nf] = (r * PH + c) * SROW + quad * 16 + kg * 128;
  }

  // ---- per-lane A global bases (elements), 4 m-frags of 16 co each ----
  const int co0 = cg * 64;
  const __bf16* wtb = wt + (size_t)b * 9 * CO * CI + kg * 64;
  int ab[4];
#pragma unroll
  for (int mf = 0; mf < 4; ++mf)
    ab[mf] = (co0 + mf * 16 + l15) * CI + quad * 8;

  f32x4 acc[4][7] = {};
  bf16x8 areg[3][4];
  // prologue prefetch: step 0 (p=0,kk=0) and step 1 (p=0,kk=1)
#pragma unroll
  for (int mf = 0; mf < 4; ++mf) areg[0][mf] = *(const bf16x8*)(wtb + ab[mf]);
#pragma unroll
  for (int mf = 0; mf < 4; ++mf) areg[1][mf] = *(const bf16x8*)(wtb + 32 + ab[mf]);

#pragma unroll
  for (int s = 0; s < 18; ++s) {
    // prefetch A for step s+2 (distance-2 ring; all indices compile-time)
    if (s < 16) {
      const int p2  = (s + 2) >> 1;
      const int kk2 = (s + 2) & 1;
      const __bf16* ap = wtb + p2 * (CO * CI) + kk2 * 32;
#pragma unroll
      for (int mf = 0; mf < 4; ++mf)
        areg[(s + 2) % 3][mf] = *(const bf16x8*)(ap + ab[mf]);
    }
    const int p  = s >> 1;
    const int kk = s & 1;
    const int kh = p / 3, kw = p - kh * 3;
    const int tapb = (kh * PH + kw) * SROW + kk * 64;   // compile-time (unrolled)
#pragma unroll
    for (int nf = 0; nf < 7; ++nf) {
      bf16x8 bfr = *(const bf16x8*)&Bsh[bbase[nf] + tapb];
#pragma unroll
      for (int mf = 0; mf < 4; ++mf)
        acc[mf][nf] = __builtin_amdgcn_mfma_f32_16x16x32_bf16(areg[s % 3][mf], bfr, acc[mf][nf], 0, 0, 0);
    }
  }

  // ---- epilogue: pair-reduce over kg via LDS (reuse halo buffer) ----
  // layout: [cg][mf*7+nf][lane] f32x4 -> 2 * 28 * 64 * 16B = 57344 B <= 63104
  __syncthreads();
  if (kg == 1) {
    char* rb = Bsh + cg * 28672;
#pragma unroll
    for (int mf = 0; mf < 4; ++mf)
#pragma unroll
      for (int nf = 0; nf < 7; ++nf)
        *(f32x4*)(rb + ((mf * 7 + nf) * 64 + lane) * 16) = acc[mf][nf];
  }
  __syncthreads();
  if (kg == 0) {
    char* rb = Bsh + cg * 28672;
    float* ob = out + (size_t)b * CO * NPIX + oh0 * 56;
#pragma unroll
    for (int mf = 0; mf < 4; ++mf) {
#pragma unroll
      for (int nf = 0; nf < 7; ++nf) {
        f32x4 part = *(const f32x4*)(rb + ((mf * 7 + nf) * 64 + lane) * 16);
        f32x4 v = acc[mf][nf] + part;
#pragma unroll
        for (int r = 0; r < 4; ++r) {
          int co = co0 + mf * 16 + quad * 4 + r;
          ob[(size_t)co * NPIX + nf * 16 + l15] = v[r];
        }
      }
    }
  }
}

// ---------------------------------------------------------------------------
extern "C" void kernel_launch(void* const* d_in, const int* in_sizes, int n_in,
                              void* d_out, int out_size, void* d_ws, size_t ws_size,
                              hipStream_t stream) {
  const float* inp = (const float*)d_in[0];   // [32,128,56,56]
  const float* eps = (const float*)d_in[1];   // [32,128,128,3,3]
  const float* psi = (const float*)d_in[2];   // [128,128,3,3]
  const float* mu  = (const float*)d_in[3];   // [128,128,3,3]

  // ws layout: wt (9,437,184 B) | inp_t (27,557,888 B)
  __bf16* wt = (__bf16*)d_ws;
  __bf16* it = (__bf16*)((char*)d_ws + 9437184);

  prep_all<<<4072, 256, 0, stream>>>(inp, eps, psi, mu, wt, it);
  bconv_gemm<<<896, 256, 0, stream>>>(wt, it, (float*)d_out);
}

// Round 2
// 160.562 us; speedup vs baseline: 1.0594x; 1.0594x over previous
//
#include <hip/hip_runtime.h>
#include <hip/hip_bf16.h>

// Problem constants
#define CO    128
#define CI    128
#define NPIX  3136   // 56*56
#define PH    58
#define PPIX  3364   // 58*58
#define HPX   232    // halo pixels per block: 4 padded rows * 58
#define SROW  272    // LDS bytes per halo pixel: 256 data + 16 pad (bank balance)

typedef __bf16 bf16x8 __attribute__((ext_vector_type(8)));
typedef float  f32x4  __attribute__((ext_vector_type(4)));

// ---------------------------------------------------------------------------
// Fused prep: [0,2048) weights | [2048,2504) border zero | [2504,4072) transpose.
// Weights phase v2: LDS-staged coalesced f32x4 loads (was 27 scalar dword
// loads/thread) and f32x4 stores (was 9x 2B stores/thread).
// ---------------------------------------------------------------------------
__global__ void prep_all(const float* __restrict__ in,
                         const float* __restrict__ eps,
                         const float* __restrict__ psi,
                         const float* __restrict__ mu,
                         __bf16* __restrict__ wt,
                         __bf16* __restrict__ it) {
  // union'd scratch: weights phase needs 3*9216 + 4608 = 32256 B;
  // transpose phase needs 64*136*2 = 17408 B.
  __shared__ __align__(16) char smem[32256];
  const int bx = blockIdx.x, tid = threadIdx.x;

  if (bx < 2048) {
    // ---- weights phase: block covers idx0..idx0+255 (one b, two co) ----
    float* Ebuf = (float*)smem;              // 2304 f32
    float* Pbuf = (float*)(smem + 9216);     // 2304 f32
    float* Mbuf = (float*)(smem + 18432);    // 2304 f32
    __bf16* Wb  = (__bf16*)(smem + 27648);   // [9][256] bf16
    const int idx0  = bx * 256;              // multiple of 256 -> ci0 = 0
    const int b     = idx0 >> 14;            // 64 blocks per b, no straddle
    const int coci0 = idx0 & 16383;          // co0*CI
    const f32x4* esrc = (const f32x4*)(eps + (size_t)idx0 * 9);
    const f32x4* psrc = (const f32x4*)(psi + (size_t)coci0 * 9);
    const f32x4* msrc = (const f32x4*)(mu  + (size_t)coci0 * 9);
#pragma unroll
    for (int i = 0; i < 3; ++i) {            // 576 f32x4 per array
      int j = i * 256 + tid;
      if (j < 576) {
        ((f32x4*)Ebuf)[j] = esrc[j];
        ((f32x4*)Pbuf)[j] = psrc[j];
        ((f32x4*)Mbuf)[j] = msrc[j];
      }
    }
    __syncthreads();
#pragma unroll
    for (int p = 0; p < 9; ++p) {
      // dword stride 9: gcd(9,32)=1 -> 2 lanes/bank -> conflict-free
      float v = Ebuf[tid * 9 + p] * __expf(Pbuf[tid * 9 + p]) + Mbuf[tid * 9 + p];
      Wb[p * 256 + tid] = (__bf16)v;
    }
    __syncthreads();
    // stores: 9 taps x 512B contiguous = 288 f32x4 chunks
    __bf16* wb = wt + (size_t)b * 9 * CO * CI + coci0;
#pragma unroll
    for (int i = 0; i < 2; ++i) {
      int s = i * 256 + tid;
      if (s < 288) {
        int p = s >> 5, j = s & 31;
        *(f32x4*)(wb + (size_t)p * CO * CI + j * 8) =
            *(const f32x4*)&Wb[p * 256 + j * 8];
      }
    }
  } else if (bx < 2504) {
    int cid = (bx - 2048) * 256 + tid;
    int pid = cid >> 4;
    int chunk = cid & 15;
    int b = pid / 228;
    int e = pid - b * 228;
    int ph, pw;
    if (e < 58)       { ph = 0;       pw = e; }
    else if (e < 116) { ph = 57;      pw = e - 58; }
    else if (e < 172) { ph = e - 115; pw = 0; }
    else              { ph = e - 171; pw = 57; }
    f32x4 z = {0.f, 0.f, 0.f, 0.f};
    *(f32x4*)&it[((size_t)b * PPIX + ph * PH + pw) * CI + chunk * 8] = z;
  } else {
    __bf16 (*T)[136] = (__bf16(*)[136])smem;   // [64][136]
    int tx = bx - 2504;
    int b  = tx / 49;
    int p0 = (tx - b * 49) * 64;
    const float* src = in + (size_t)b * CI * NPIX;
#pragma unroll
    for (int jj = 0; jj < 8; ++jj) {
      int c = jj * 256 + tid;
      int ci = c >> 4, xc = c & 15;
      float4 v = *(const float4*)(src + (size_t)ci * NPIX + p0 + xc * 4);
      T[xc * 4 + 0][ci] = (__bf16)v.x;
      T[xc * 4 + 1][ci] = (__bf16)v.y;
      T[xc * 4 + 2][ci] = (__bf16)v.z;
      T[xc * 4 + 3][ci] = (__bf16)v.w;
    }
    __syncthreads();
    __bf16* dstb = it + (size_t)b * PPIX * CI;
#pragma unroll
    for (int jj = 0; jj < 4; ++jj) {
      int c = jj * 256 + tid;
      int pl = c >> 4, xc = c & 15;
      int pix = p0 + pl;
      int oh = pix / 56, ow = pix - oh * 56;
      int ppix = (oh + 1) * PH + (ow + 1);
      *(f32x4*)&dstb[(size_t)ppix * CI + xc * 8] = *(const f32x4*)&T[pl][xc * 8];
    }
  }
}

// ---------------------------------------------------------------------------
// GEMM/conv, barrier-free K-loop ("B-stationary halo") — round-0 structure:
//   block = 128 co x 112 n (2 full image rows), 4 waves of 32co x 112n.
//   Prologue: stage the 4-row halo (232 px x 256B, contiguous in it[]) into
//   LDS once (272B padded rows -> balanced banks), ONE __syncthreads.
//   K-loop (9 taps x 4 ci-slices = 36 steps): B from LDS at tap offsets,
//   A direct global->VGPR with 1-step register prefetch. NO barriers.
//   Grid 28 tiles x 32 batch = 896 blocks; LDS 63104B -> 2 blocks/CU.
// ---------------------------------------------------------------------------
__global__ __launch_bounds__(256) void bconv_gemm(
    const __bf16* __restrict__ wt,   // [b][9][128 co][128 ci]
    const __bf16* __restrict__ it,   // [b][3364 pix][128 ci]
    float* __restrict__ out) {       // [b][128 co][3136 n]
  __shared__ __align__(16) char Bsh[HPX * SROW];   // 63104 B
  const int tid  = threadIdx.x;
  const int w    = tid >> 6;
  const int lane = tid & 63;
  const int quad = lane >> 4;
  const int l15  = lane & 15;

  // Decode: lin = x + 8*(tile*4 + bhi); b = x + 8*bhi  -> same-b blocks share an XCD
  const int lin = blockIdx.x;
  const int x   = lin & 7;
  const int j   = lin >> 3;          // 0..111
  const int bhi = j & 3;
  const int tile = j >> 2;           // 0..27
  const int b   = x + 8 * bhi;
  const int oh0 = tile * 2;          // first output row of this tile

  // ---- prologue: stage halo (padded rows oh0..oh0+3, contiguous) ----
  const __bf16* hsrc = it + ((size_t)b * PPIX + oh0 * PH) * CI;
#pragma unroll
  for (int i = 0; i < 15; ++i) {
    int idx = i * 256 + tid;                 // 16B chunk id, 3712 total
    if (idx < HPX * 16) {
      int px = idx >> 4, sub = idx & 15;
      f32x4 v = *(const f32x4*)(hsrc + (size_t)idx * 8);
      *(f32x4*)&Bsh[px * SROW + sub * 16] = v;
    }
  }
  __syncthreads();

  // ---- per-lane B fragment LDS byte-bases (tap (0,0), ci-slice 0) ----
  int bbase[7];
#pragma unroll
  for (int nf = 0; nf < 7; ++nf) {
    int n = nf * 16 + l15;                   // 0..111
    int r = (n >= 56) ? 1 : 0;
    int c = n - r * 56;
    bbase[nf] = (r * PH + c) * SROW + quad * 16;
  }

  // ---- per-lane A global bases (elements) ----
  const int co0 = w * 32;
  const __bf16* wtb = wt + (size_t)b * 9 * CO * CI;
  const int ab0 = (co0 +      l15) * CI + quad * 8;
  const int ab1 = (co0 + 16 + l15) * CI + quad * 8;

  f32x4 acc[2][7] = {};
  bf16x8 acur[2], anxt[2];
  acur[0] = *(const bf16x8*)(wtb + ab0);
  acur[1] = *(const bf16x8*)(wtb + ab1);

#pragma unroll
  for (int s = 0; s < 36; ++s) {
    const int p   = s >> 2;
    const int ci0 = (s & 3) << 5;
    // prefetch A for step s+1 (register double-buffer; no barrier anywhere)
    if (s < 35) {
      const int pn   = (s + 1) >> 2;
      const int ci0n = ((s + 1) & 3) << 5;
      const __bf16* ap = wtb + pn * (CO * CI) + ci0n;
      anxt[0] = *(const bf16x8*)(ap + ab0);
      anxt[1] = *(const bf16x8*)(ap + ab1);
    }
    const int kh = p / 3, kw = p - kh * 3;
    const int tapb = (kh * PH + kw) * SROW + ci0 * 2;   // compile-time (unrolled)
#pragma unroll
    for (int nf = 0; nf < 7; ++nf) {
      bf16x8 bfr = *(const bf16x8*)&Bsh[bbase[nf] + tapb];
      acc[0][nf] = __builtin_amdgcn_mfma_f32_16x16x32_bf16(acur[0], bfr, acc[0][nf], 0, 0, 0);
      acc[1][nf] = __builtin_amdgcn_mfma_f32_16x16x32_bf16(acur[1], bfr, acc[1][nf], 0, 0, 0);
    }
    acur[0] = anxt[0];
    acur[1] = anxt[1];
  }

  // ---- epilogue: C col(l15)=n, row(quad*4+r)=co; n_global = oh0*56 + n ----
  float* ob = out + (size_t)b * CO * NPIX + oh0 * 56;
#pragma unroll
  for (int mf = 0; mf < 2; ++mf) {
#pragma unroll
    for (int nf = 0; nf < 7; ++nf) {
#pragma unroll
      for (int r = 0; r < 4; ++r) {
        int co = co0 + mf * 16 + quad * 4 + r;
        ob[(size_t)co * NPIX + nf * 16 + l15] = acc[mf][nf][r];
      }
    }
  }
}

// ---------------------------------------------------------------------------
extern "C" void kernel_launch(void* const* d_in, const int* in_sizes, int n_in,
                              void* d_out, int out_size, void* d_ws, size_t ws_size,
                              hipStream_t stream) {
  const float* inp = (const float*)d_in[0];   // [32,128,56,56]
  const float* eps = (const float*)d_in[1];   // [32,128,128,3,3]
  const float* psi = (const float*)d_in[2];   // [128,128,3,3]
  const float* mu  = (const float*)d_in[3];   // [128,128,3,3]

  // ws layout: wt (9,437,184 B) | inp_t (27,557,888 B)
  __bf16* wt = (__bf16*)d_ws;
  __bf16* it = (__bf16*)((char*)d_ws + 9437184);

  prep_all<<<4072, 256, 0, stream>>>(inp, eps, psi, mu, wt, it);
  bconv_gemm<<<896, 256, 0, stream>>>(wt, it, (float*)d_out);
}

// Round 3
// 156.687 us; speedup vs baseline: 1.0855x; 1.0247x over previous
//
#include <hip/hip_runtime.h>
#include <hip/hip_bf16.h>

// Problem constants
#define CO    128
#define CI    128
#define NPIX  3136   // 56*56
#define PH    58
#define PPIX  3364   // 58*58
#define HPX   232    // halo pixels per block: 4 padded rows * 58
#define SROW2 144    // LDS bytes per halo pixel per ci-half: 128 data + 16 pad

typedef __bf16 bf16x8 __attribute__((ext_vector_type(8)));
typedef float  f32x4  __attribute__((ext_vector_type(4)));

// ---------------------------------------------------------------------------
// Fused prep: [0,2048) weights | [2048,2504) border zero | [2504,4072) transpose.
// it layout v2: [b][ci-half h][3364 px][64 ci]  (half-planes contiguous so
// bconv can stage one 64-ci half of the halo with fully coalesced loads).
// ---------------------------------------------------------------------------
__global__ void prep_all(const float* __restrict__ in,
                         const float* __restrict__ eps,
                         const float* __restrict__ psi,
                         const float* __restrict__ mu,
                         __bf16* __restrict__ wt,
                         __bf16* __restrict__ it) {
  __shared__ __align__(16) char smem[32256];
  const int bx = blockIdx.x, tid = threadIdx.x;

  if (bx < 2048) {
    // ---- weights phase: block covers idx0..idx0+255 (one b, two co) ----
    float* Ebuf = (float*)smem;              // 2304 f32
    float* Pbuf = (float*)(smem + 9216);     // 2304 f32
    float* Mbuf = (float*)(smem + 18432);    // 2304 f32
    __bf16* Wb  = (__bf16*)(smem + 27648);   // [9][256] bf16
    const int idx0  = bx * 256;              // multiple of 256 -> ci0 = 0
    const int b     = idx0 >> 14;            // 64 blocks per b, no straddle
    const int coci0 = idx0 & 16383;          // co0*CI
    const f32x4* esrc = (const f32x4*)(eps + (size_t)idx0 * 9);
    const f32x4* psrc = (const f32x4*)(psi + (size_t)coci0 * 9);
    const f32x4* msrc = (const f32x4*)(mu  + (size_t)coci0 * 9);
#pragma unroll
    for (int i = 0; i < 3; ++i) {            // 576 f32x4 per array
      int j = i * 256 + tid;
      if (j < 576) {
        ((f32x4*)Ebuf)[j] = esrc[j];
        ((f32x4*)Pbuf)[j] = psrc[j];
        ((f32x4*)Mbuf)[j] = msrc[j];
      }
    }
    __syncthreads();
#pragma unroll
    for (int p = 0; p < 9; ++p) {
      float v = Ebuf[tid * 9 + p] * __expf(Pbuf[tid * 9 + p]) + Mbuf[tid * 9 + p];
      Wb[p * 256 + tid] = (__bf16)v;
    }
    __syncthreads();
    __bf16* wb = wt + (size_t)b * 9 * CO * CI + coci0;
#pragma unroll
    for (int i = 0; i < 2; ++i) {
      int s = i * 256 + tid;
      if (s < 288) {
        int p = s >> 5, j = s & 31;
        *(f32x4*)(wb + (size_t)p * CO * CI + j * 8) =
            *(const f32x4*)&Wb[p * 256 + j * 8];
      }
    }
  } else if (bx < 2504) {
    int cid = (bx - 2048) * 256 + tid;
    int pid = cid >> 4;
    int chunk = cid & 15;                    // 16 chunks of 16B per pixel
    int h  = chunk >> 3;                     // ci-half
    int c8 = chunk & 7;
    int b = pid / 228;
    int e = pid - b * 228;
    int ph, pw;
    if (e < 58)       { ph = 0;       pw = e; }
    else if (e < 116) { ph = 57;      pw = e - 58; }
    else if (e < 172) { ph = e - 115; pw = 0; }
    else              { ph = e - 171; pw = 57; }
    f32x4 z = {0.f, 0.f, 0.f, 0.f};
    *(f32x4*)&it[((size_t)(b * 2 + h) * PPIX + ph * PH + pw) * 64 + c8 * 8] = z;
  } else {
    __bf16 (*T)[136] = (__bf16(*)[136])smem;   // [64][136]
    int tx = bx - 2504;
    int b  = tx / 49;
    int p0 = (tx - b * 49) * 64;
    const float* src = in + (size_t)b * CI * NPIX;
#pragma unroll
    for (int jj = 0; jj < 8; ++jj) {
      int c = jj * 256 + tid;
      int ci = c >> 4, xc = c & 15;
      float4 v = *(const float4*)(src + (size_t)ci * NPIX + p0 + xc * 4);
      T[xc * 4 + 0][ci] = (__bf16)v.x;
      T[xc * 4 + 1][ci] = (__bf16)v.y;
      T[xc * 4 + 2][ci] = (__bf16)v.z;
      T[xc * 4 + 3][ci] = (__bf16)v.w;
    }
    __syncthreads();
#pragma unroll
    for (int jj = 0; jj < 4; ++jj) {
      int c = jj * 256 + tid;
      int pl = c >> 4, xc = c & 15;
      int h  = xc >> 3;
      int c8 = xc & 7;
      int pix = p0 + pl;
      int oh = pix / 56, ow = pix - oh * 56;
      int ppix = (oh + 1) * PH + (ow + 1);
      *(f32x4*)&it[((size_t)(b * 2 + h) * PPIX + ppix) * 64 + c8 * 8] =
          *(const f32x4*)&T[pl][xc * 8];
    }
  }
}

// ---------------------------------------------------------------------------
// GEMM/conv, ci-split halo for 4 blocks/CU (16 waves/CU, single-pass grid):
//   block = 128 co x 112 n (2 full image rows), 4 waves of 32co x 112n.
//   Stage 64-ci half of the 4-row halo (232 px x 128B -> 144B padded rows,
//   33.4KB) -> 4 blocks/CU resident. K-loop = 2 halves x (9 taps x 2
//   ci-chunks) = 36 steps; restage at the midpoint (2 barriers). B from LDS,
//   A direct global->VGPR with 1-step register prefetch; no other barriers.
//   Grid 28 tiles x 32 batch = 896 blocks, all resident (capacity 1024).
// ---------------------------------------------------------------------------
__global__ __launch_bounds__(256, 4) void bconv_gemm(
    const __bf16* __restrict__ wt,   // [b][9][128 co][128 ci]
    const __bf16* __restrict__ it,   // [b][2 h][3364 px][64 ci]
    float* __restrict__ out) {       // [b][128 co][3136 n]
  __shared__ __align__(16) char Bsh[HPX * SROW2];   // 33408 B
  const int tid  = threadIdx.x;
  const int w    = tid >> 6;
  const int lane = tid & 63;
  const int quad = lane >> 4;
  const int l15  = lane & 15;

  // Decode: lin = x + 8*(tile*4 + bhi); b = x + 8*bhi  -> same-b blocks share an XCD
  const int lin = blockIdx.x;
  const int x   = lin & 7;
  const int j   = lin >> 3;          // 0..111
  const int bhi = j & 3;
  const int tile = j >> 2;           // 0..27
  const int b   = x + 8 * bhi;
  const int oh0 = tile * 2;          // first output row of this tile

  // ---- halo staging for ci-half h: 232 px x 8 chunks of 16B = 1856 chunks ----
  const __bf16* hsrc0 = it + ((size_t)(b * 2 + 0) * PPIX + oh0 * PH) * 64;
  const __bf16* hsrc1 = it + ((size_t)(b * 2 + 1) * PPIX + oh0 * PH) * 64;
#pragma unroll
  for (int i = 0; i < 8; ++i) {
    int idx = i * 256 + tid;
    if (idx < HPX * 8) {
      int px = idx >> 3, sub = idx & 7;
      *(f32x4*)&Bsh[px * SROW2 + sub * 16] = *(const f32x4*)(hsrc0 + (size_t)idx * 8);
    }
  }
  __syncthreads();

  // ---- per-lane B fragment LDS byte-bases (tap (0,0), kk=0) ----
  int bbase[7];
#pragma unroll
  for (int nf = 0; nf < 7; ++nf) {
    int n = nf * 16 + l15;                   // 0..111
    int r = (n >= 56) ? 1 : 0;
    int c = n - r * 56;
    bbase[nf] = (r * PH + c) * SROW2 + quad * 16;
  }

  // ---- per-lane A global bases (elements) ----
  const int co0 = w * 32;
  const __bf16* wtb = wt + (size_t)b * 9 * CO * CI;
  const int ab0 = (co0 +      l15) * CI + quad * 8;
  const int ab1 = (co0 + 16 + l15) * CI + quad * 8;

  f32x4 acc[2][7] = {};
  bf16x8 acur[2], anxt[2];
  acur[0] = *(const bf16x8*)(wtb + ab0);
  acur[1] = *(const bf16x8*)(wtb + ab1);

  // step s: h = s/18, p = (s%18)>>1, kk = s&1
  // A element offset: p*CO*CI + h*64 + kk*32 ; B LDS tap: (kh*PH+kw)*SROW2 + kk*64
#pragma unroll
  for (int s = 0; s < 36; ++s) {
    if (s == 18) {
      __syncthreads();                       // all waves done reading half 0
#pragma unroll
      for (int i = 0; i < 8; ++i) {
        int idx = i * 256 + tid;
        if (idx < HPX * 8) {
          int px = idx >> 3, sub = idx & 7;
          *(f32x4*)&Bsh[px * SROW2 + sub * 16] = *(const f32x4*)(hsrc1 + (size_t)idx * 8);
        }
      }
      __syncthreads();
    }
    const int s2 = s % 18;
    const int p  = s2 >> 1;
    const int kk = s2 & 1;
    // prefetch A for step s+1 (register double-buffer)
    if (s < 35) {
      const int sn  = s + 1;
      const int hn  = sn / 18;
      const int s2n = sn % 18;
      const int pn  = s2n >> 1;
      const int kkn = s2n & 1;
      const __bf16* ap = wtb + pn * (CO * CI) + hn * 64 + kkn * 32;
      anxt[0] = *(const bf16x8*)(ap + ab0);
      anxt[1] = *(const bf16x8*)(ap + ab1);
    }
    const int kh = p / 3, kw = p - kh * 3;
    const int tapb = (kh * PH + kw) * SROW2 + kk * 64;   // compile-time (unrolled)
#pragma unroll
    for (int nf = 0; nf < 7; ++nf) {
      bf16x8 bfr = *(const bf16x8*)&Bsh[bbase[nf] + tapb];
      acc[0][nf] = __builtin_amdgcn_mfma_f32_16x16x32_bf16(acur[0], bfr, acc[0][nf], 0, 0, 0);
      acc[1][nf] = __builtin_amdgcn_mfma_f32_16x16x32_bf16(acur[1], bfr, acc[1][nf], 0, 0, 0);
    }
    acur[0] = anxt[0];
    acur[1] = anxt[1];
  }

  // ---- epilogue: C col(l15)=n, row(quad*4+r)=co; n_global = oh0*56 + n ----
  float* ob = out + (size_t)b * CO * NPIX + oh0 * 56;
#pragma unroll
  for (int mf = 0; mf < 2; ++mf) {
#pragma unroll
    for (int nf = 0; nf < 7; ++nf) {
#pragma unroll
      for (int r = 0; r < 4; ++r) {
        int co = co0 + mf * 16 + quad * 4 + r;
        ob[(size_t)co * NPIX + nf * 16 + l15] = acc[mf][nf][r];
      }
    }
  }
}

// ---------------------------------------------------------------------------
extern "C" void kernel_launch(void* const* d_in, const int* in_sizes, int n_in,
                              void* d_out, int out_size, void* d_ws, size_t ws_size,
                              hipStream_t stream) {
  const float* inp = (const float*)d_in[0];   // [32,128,56,56]
  const float* eps = (const float*)d_in[1];   // [32,128,128,3,3]
  const float* psi = (const float*)d_in[2];   // [128,128,3,3]
  const float* mu  = (const float*)d_in[3];   // [128,128,3,3]

  // ws layout: wt (9,437,184 B) | it (27,557,888 B)
  __bf16* wt = (__bf16*)d_ws;
  __bf16* it = (__bf16*)((char*)d_ws + 9437184);

  prep_all<<<4072, 256, 0, stream>>>(inp, eps, psi, mu, wt, it);
  bconv_gemm<<<896, 256, 0, stream>>>(wt, it, (float*)d_out);
}

// Round 4
// 156.403 us; speedup vs baseline: 1.0875x; 1.0018x over previous
//
#include <hip/hip_runtime.h>
#include <hip/hip_bf16.h>

// Problem constants
#define CO    128
#define CI    128
#define NPIX  3136   // 56*56
#define PH    58
#define PPIX  3364   // 58*58
#define HPX   232    // halo pixels per block: 4 padded rows * 58
#define SROW2 144    // LDS bytes per halo pixel per ci-half: 128 data + 16 pad

typedef __bf16 bf16x8 __attribute__((ext_vector_type(8)));
typedef float  f32x4  __attribute__((ext_vector_type(4)));

// ---------------------------------------------------------------------------
// Fused prep: [0,2048) weights | [2048,2504) border zero | [2504,4072) transpose.
// it layout v2: [b][ci-half h][3364 px][64 ci].
// ---------------------------------------------------------------------------
__global__ void prep_all(const float* __restrict__ in,
                         const float* __restrict__ eps,
                         const float* __restrict__ psi,
                         const float* __restrict__ mu,
                         __bf16* __restrict__ wt,
                         __bf16* __restrict__ it) {
  __shared__ __align__(16) char smem[32256];
  const int bx = blockIdx.x, tid = threadIdx.x;

  if (bx < 2048) {
    // ---- weights phase: block covers idx0..idx0+255 (one b, two co) ----
    float* Ebuf = (float*)smem;              // 2304 f32
    float* Pbuf = (float*)(smem + 9216);     // 2304 f32
    float* Mbuf = (float*)(smem + 18432);    // 2304 f32
    __bf16* Wb  = (__bf16*)(smem + 27648);   // [9][256] bf16
    const int idx0  = bx * 256;              // multiple of 256 -> ci0 = 0
    const int b     = idx0 >> 14;            // 64 blocks per b, no straddle
    const int coci0 = idx0 & 16383;          // co0*CI
    const f32x4* esrc = (const f32x4*)(eps + (size_t)idx0 * 9);
    const f32x4* psrc = (const f32x4*)(psi + (size_t)coci0 * 9);
    const f32x4* msrc = (const f32x4*)(mu  + (size_t)coci0 * 9);
#pragma unroll
    for (int i = 0; i < 3; ++i) {            // 576 f32x4 per array
      int j = i * 256 + tid;
      if (j < 576) {
        ((f32x4*)Ebuf)[j] = esrc[j];
        ((f32x4*)Pbuf)[j] = psrc[j];
        ((f32x4*)Mbuf)[j] = msrc[j];
      }
    }
    __syncthreads();
#pragma unroll
    for (int p = 0; p < 9; ++p) {
      float v = Ebuf[tid * 9 + p] * __expf(Pbuf[tid * 9 + p]) + Mbuf[tid * 9 + p];
      Wb[p * 256 + tid] = (__bf16)v;
    }
    __syncthreads();
    __bf16* wb = wt + (size_t)b * 9 * CO * CI + coci0;
#pragma unroll
    for (int i = 0; i < 2; ++i) {
      int s = i * 256 + tid;
      if (s < 288) {
        int p = s >> 5, j = s & 31;
        *(f32x4*)(wb + (size_t)p * CO * CI + j * 8) =
            *(const f32x4*)&Wb[p * 256 + j * 8];
      }
    }
  } else if (bx < 2504) {
    int cid = (bx - 2048) * 256 + tid;
    int pid = cid >> 4;
    int chunk = cid & 15;                    // 16 chunks of 16B per pixel
    int h  = chunk >> 3;                     // ci-half
    int c8 = chunk & 7;
    int b = pid / 228;
    int e = pid - b * 228;
    int ph, pw;
    if (e < 58)       { ph = 0;       pw = e; }
    else if (e < 116) { ph = 57;      pw = e - 58; }
    else if (e < 172) { ph = e - 115; pw = 0; }
    else              { ph = e - 171; pw = 57; }
    f32x4 z = {0.f, 0.f, 0.f, 0.f};
    *(f32x4*)&it[((size_t)(b * 2 + h) * PPIX + ph * PH + pw) * 64 + c8 * 8] = z;
  } else {
    __bf16 (*T)[136] = (__bf16(*)[136])smem;   // [64][136]
    int tx = bx - 2504;
    int b  = tx / 49;
    int p0 = (tx - b * 49) * 64;
    const float* src = in + (size_t)b * CI * NPIX;
#pragma unroll
    for (int jj = 0; jj < 8; ++jj) {
      int c = jj * 256 + tid;
      int ci = c >> 4, xc = c & 15;
      float4 v = *(const float4*)(src + (size_t)ci * NPIX + p0 + xc * 4);
      T[xc * 4 + 0][ci] = (__bf16)v.x;
      T[xc * 4 + 1][ci] = (__bf16)v.y;
      T[xc * 4 + 2][ci] = (__bf16)v.z;
      T[xc * 4 + 3][ci] = (__bf16)v.w;
    }
    __syncthreads();
#pragma unroll
    for (int jj = 0; jj < 4; ++jj) {
      int c = jj * 256 + tid;
      int pl = c >> 4, xc = c & 15;
      int h  = xc >> 3;
      int c8 = xc & 7;
      int pix = p0 + pl;
      int oh = pix / 56, ow = pix - oh * 56;
      int ppix = (oh + 1) * PH + (ow + 1);
      *(f32x4*)&it[((size_t)(b * 2 + h) * PPIX + ppix) * 64 + c8 * 8] =
          *(const f32x4*)&T[pl][xc * 8];
    }
  }
}

// ---------------------------------------------------------------------------
// GEMM/conv, ci-split halo, 4 blocks/CU + distance-2 A ring + setprio:
//   block = 128 co x 112 n, 4 waves of 32co x 112n.
//   Stage 64-ci half of the 4-row halo (33.4KB LDS). K-loop = 36 steps
//   (2 halves x 9 taps x 2 ci-chunks); restage at midpoint (2 barriers).
//   A: global->VGPR, distance-2 register ring (covers L2/L3 latency under
//   load). Per-step compute cluster wrapped in s_setprio(1) (T5: waves are
//   phase-diverse since the loop is barrier-free).
// ---------------------------------------------------------------------------
__global__ __launch_bounds__(256, 4) void bconv_gemm(
    const __bf16* __restrict__ wt,   // [b][9][128 co][128 ci]
    const __bf16* __restrict__ it,   // [b][2 h][3364 px][64 ci]
    float* __restrict__ out) {       // [b][128 co][3136 n]
  __shared__ __align__(16) char Bsh[HPX * SROW2];   // 33408 B
  const int tid  = threadIdx.x;
  const int w    = tid >> 6;
  const int lane = tid & 63;
  const int quad = lane >> 4;
  const int l15  = lane & 15;

  // Decode: lin = x + 8*(tile*4 + bhi); b = x + 8*bhi  -> same-b blocks share an XCD
  const int lin = blockIdx.x;
  const int x   = lin & 7;
  const int j   = lin >> 3;          // 0..111
  const int bhi = j & 3;
  const int tile = j >> 2;           // 0..27
  const int b   = x + 8 * bhi;
  const int oh0 = tile * 2;          // first output row of this tile

  // ---- halo staging for ci-half 0 ----
  const __bf16* hsrc0 = it + ((size_t)(b * 2 + 0) * PPIX + oh0 * PH) * 64;
  const __bf16* hsrc1 = it + ((size_t)(b * 2 + 1) * PPIX + oh0 * PH) * 64;
#pragma unroll
  for (int i = 0; i < 8; ++i) {
    int idx = i * 256 + tid;
    if (idx < HPX * 8) {
      int px = idx >> 3, sub = idx & 7;
      *(f32x4*)&Bsh[px * SROW2 + sub * 16] = *(const f32x4*)(hsrc0 + (size_t)idx * 8);
    }
  }
  __syncthreads();

  // ---- per-lane B fragment LDS byte-bases (tap (0,0), kk=0) ----
  int bbase[7];
#pragma unroll
  for (int nf = 0; nf < 7; ++nf) {
    int n = nf * 16 + l15;                   // 0..111
    int r = (n >= 56) ? 1 : 0;
    int c = n - r * 56;
    bbase[nf] = (r * PH + c) * SROW2 + quad * 16;
  }

  // ---- per-lane A global bases (elements) ----
  const int co0 = w * 32;
  const __bf16* wtb = wt + (size_t)b * 9 * CO * CI;
  const int ab0 = (co0 +      l15) * CI + quad * 8;
  const int ab1 = (co0 + 16 + l15) * CI + quad * 8;

  f32x4 acc[2][7] = {};
  // distance-2 A-prefetch ring (statically indexed under full unroll)
  bf16x8 areg[3][2];
  // step t: h = t/18, s2 = t%18, p = s2>>1, kk = s2&1
  // A offset = p*CO*CI + h*64 + kk*32
  areg[0][0] = *(const bf16x8*)(wtb + ab0);        // t=0: p0 kk0 h0
  areg[0][1] = *(const bf16x8*)(wtb + ab1);
  areg[1][0] = *(const bf16x8*)(wtb + 32 + ab0);   // t=1: p0 kk1 h0
  areg[1][1] = *(const bf16x8*)(wtb + 32 + ab1);

#pragma unroll
  for (int s = 0; s < 36; ++s) {
    if (s == 18) {
      __syncthreads();                       // all waves done reading half 0
#pragma unroll
      for (int i = 0; i < 8; ++i) {
        int idx = i * 256 + tid;
        if (idx < HPX * 8) {
          int px = idx >> 3, sub = idx & 7;
          *(f32x4*)&Bsh[px * SROW2 + sub * 16] = *(const f32x4*)(hsrc1 + (size_t)idx * 8);
        }
      }
      __syncthreads();
    }
    // prefetch A for step s+2 (distance-2 covers L2/L3 latency)
    if (s < 34) {
      const int tn  = s + 2;
      const int hn  = tn / 18;
      const int s2n = tn % 18;
      const int pn  = s2n >> 1;
      const int kkn = s2n & 1;
      const __bf16* ap = wtb + pn * (CO * CI) + hn * 64 + kkn * 32;
      areg[tn % 3][0] = *(const bf16x8*)(ap + ab0);
      areg[tn % 3][1] = *(const bf16x8*)(ap + ab1);
    }
    const int s2 = s % 18;
    const int p  = s2 >> 1;
    const int kk = s2 & 1;
    const int kh = p / 3, kw = p - kh * 3;
    const int tapb = (kh * PH + kw) * SROW2 + kk * 64;   // compile-time (unrolled)
    __builtin_amdgcn_s_setprio(1);
#pragma unroll
    for (int nf = 0; nf < 7; ++nf) {
      bf16x8 bfr = *(const bf16x8*)&Bsh[bbase[nf] + tapb];
      acc[0][nf] = __builtin_amdgcn_mfma_f32_16x16x32_bf16(areg[s % 3][0], bfr, acc[0][nf], 0, 0, 0);
      acc[1][nf] = __builtin_amdgcn_mfma_f32_16x16x32_bf16(areg[s % 3][1], bfr, acc[1][nf], 0, 0, 0);
    }
    __builtin_amdgcn_s_setprio(0);
  }

  // ---- epilogue: C col(l15)=n, row(quad*4+r)=co; n_global = oh0*56 + n ----
  float* ob = out + (size_t)b * CO * NPIX + oh0 * 56;
#pragma unroll
  for (int mf = 0; mf < 2; ++mf) {
#pragma unroll
    for (int nf = 0; nf < 7; ++nf) {
#pragma unroll
      for (int r = 0; r < 4; ++r) {
        int co = co0 + mf * 16 + quad * 4 + r;
        ob[(size_t)co * NPIX + nf * 16 + l15] = acc[mf][nf][r];
      }
    }
  }
}

// ---------------------------------------------------------------------------
extern "C" void kernel_launch(void* const* d_in, const int* in_sizes, int n_in,
                              void* d_out, int out_size, void* d_ws, size_t ws_size,
                              hipStream_t stream) {
  const float* inp = (const float*)d_in[0];   // [32,128,56,56]
  const float* eps = (const float*)d_in[1];   // [32,128,128,3,3]
  const float* psi = (const float*)d_in[2];   // [128,128,3,3]
  const float* mu  = (const float*)d_in[3];   // [128,128,3,3]

  // ws layout: wt (9,437,184 B) | it (27,557,888 B)
  __bf16* wt = (__bf16*)d_ws;
  __bf16* it = (__bf16*)((char*)d_ws + 9437184);

  prep_all<<<4072, 256, 0, stream>>>(inp, eps, psi, mu, wt, it);
  bconv_gemm<<<896, 256, 0, stream>>>(wt, it, (float*)d_out);
}